// Round 1
// baseline (63.890 us; speedup 1.0000x reference)
//
#include <hip/hip_runtime.h>

// LPC residual: per 160-sample frame, autocorrelation(0..16) -> Levinson-Durbin
// -> FIR res[t] = sum_{j=0..16} a[j] * f[t-j]  (a[0]=1, f[t<0]=0).
//
// Mapping: one wave64 per frame, 4 waves per 256-thread block.
// Frame staged in LDS (640B per wave). Levinson is redundant across lanes
// (costs one instruction stream per wave regardless).

#define FS 160
#define ORD 16
#define WPB 4  // waves (frames) per block

__global__ __launch_bounds__(256) void lpc_kernel(const float* __restrict__ x,
                                                  float* __restrict__ out,
                                                  int nframes) {
    __shared__ float sf[WPB][FS];
    const int wv = threadIdx.x >> 6;
    const int lane = threadIdx.x & 63;
    const int frame = blockIdx.x * WPB + wv;
    const bool valid = frame < nframes;
    float* s = sf[wv];

    if (valid) {
        const float* fp = x + (size_t)frame * FS;
        s[lane] = fp[lane];
        s[lane + 64] = fp[lane + 64];
        if (lane < FS - 128) s[lane + 128] = fp[lane + 128];
    }
    __syncthreads();
    if (!valid) return;

    // ---- autocorrelation: r[j] = sum_t f[t]*f[t+j] ----
    float r[ORD + 1];
#pragma unroll
    for (int j = 0; j <= ORD; ++j) {
        float p = 0.0f;
#pragma unroll
        for (int c = 0; c < 3; ++c) {
            int t = lane + 64 * c;
            if (t < FS - j) p += s[t] * s[t + j];
        }
        r[j] = p;
    }
    // 64-lane butterfly reduction; result broadcast to all lanes
#pragma unroll
    for (int off = 32; off >= 1; off >>= 1) {
#pragma unroll
        for (int j = 0; j <= ORD; ++j) r[j] += __shfl_xor(r[j], off, 64);
    }

    // ---- Levinson-Durbin (matches reference exactly) ----
    float a[ORD + 1], tmp[ORD + 1];
    a[0] = 1.0f;
#pragma unroll
    for (int j = 1; j <= ORD; ++j) a[j] = 0.0f;
    float e = r[0];
#pragma unroll
    for (int i = 1; i <= ORD; ++i) {
        float acc = r[i];
#pragma unroll
        for (int m = 1; m < i; ++m) acc -= a[m] * r[i - m];
        float k = acc / e;
#pragma unroll
        for (int m = 1; m < i; ++m) tmp[m] = a[m] - k * a[i - m];
#pragma unroll
        for (int m = 1; m < i; ++m) a[m] = tmp[m];
        a[i] = k;
        e *= (1.0f - k * k);
    }

    // ---- FIR: res[t] = sum_j a[j] * f[t-j] ----
    float* op = out + (size_t)frame * FS;
#pragma unroll
    for (int c = 0; c < 3; ++c) {
        int t = lane + 64 * c;
        if (t < FS) {
            float acc2 = 0.0f;
#pragma unroll
            for (int j = 0; j <= ORD; ++j) {
                float v = (t >= j) ? s[t - j] : 0.0f;
                acc2 += a[j] * v;
            }
            op[t] = acc2;
        }
    }
}

extern "C" void kernel_launch(void* const* d_in, const int* in_sizes, int n_in,
                              void* d_out, int out_size, void* d_ws, size_t ws_size,
                              hipStream_t stream) {
    const float* x = (const float*)d_in[0];
    float* out = (float*)d_out;
    const int total = in_sizes[0];          // 32 * 160000 = 5,120,000
    const int nframes = total / FS;         // 32,000
    const int blocks = (nframes + WPB - 1) / WPB;  // 8,000
    lpc_kernel<<<blocks, 256, 0, stream>>>(x, out, nframes);
}

// Round 2
// 18.606 us; speedup vs baseline: 3.4339x; 3.4339x over previous
//
#include <hip/hip_runtime.h>

// LPC residual, round 2: 8 lanes/frame, 8 frames/wave, 4 waves/block.
// Zero-padded LDS frame slots kill boundary predication; register sliding
// windows (9x ds_read_b128) feed all FMAs; Levinson amortized over 8 frames
// per wave with v_rcp_f32 divides.

#define FS 160
#define ORD 16
#define LPF 8            // lanes per frame group
#define FPW 8            // frames per wave
#define WPB 4            // waves per block
#define FPB (FPW * WPB)  // 32 frames per block
#define SLOT 196         // floats per frame slot: 16 front pad + 160 + 16 back pad + 4 bank stagger
#define CHUNK 20         // t-positions per lane

__global__ __launch_bounds__(256) void lpc_kernel(const float* __restrict__ x,
                                                  float* __restrict__ out,
                                                  int nframes) {
    __shared__ float sf[WPB * FPW * SLOT];  // 25088 B
    const int tid = threadIdx.x;
    const int wv = tid >> 6;
    const int lane = tid & 63;
    const int g = lane >> 3;   // frame group within wave (0..7)
    const int li = lane & 7;   // lane within group (0..7)
    const int wframe0 = (blockIdx.x * WPB + wv) * FPW;
    if (wframe0 >= nframes) return;  // grid sized so full waves only (32000 % 32 == 0)
    float* s = sf + wv * FPW * SLOT;

    // ---- stage 8 frames (1280 contiguous floats = 320 float4, 5 per lane) ----
    const float4* xin = (const float4*)(x + (size_t)wframe0 * FS);
#pragma unroll
    for (int c = 0; c < 5; ++c) {
        int i = lane + 64 * c;       // float4 index within wave's chunk
        int gfo = 4 * i;             // float offset within 1280
        int f = gfo / FS;            // frame 0..7
        int p = gfo - f * FS;        // position within frame, multiple of 4
        float4 v = xin[i];
        *(float4*)(s + f * SLOT + 16 + p) = v;
    }
    // ---- zero pads: per frame, front [0,16) and back [176,192) ----
#pragma unroll
    for (int c = 0; c < 4; ++c) {
        int z = lane + 64 * c;       // 0..255 = 8 frames x 32 pad slots
        int f = z >> 5;
        int q = z & 31;
        int off = (q < 16) ? q : (q + 160);  // front or back pad
        s[f * SLOT + off] = 0.0f;
    }
    __syncthreads();

    const float* fb = s + g * SLOT;  // this group's frame slot

    // ---- autocorrelation from register window [c, c+36), c = 20*li ----
    float w[36];
    {
        const float* wa = fb + 16 + CHUNK * li;  // 16B-aligned
#pragma unroll
        for (int m = 0; m < 36; m += 4)
            *(float4*)(w + m) = *(const float4*)(wa + m);
    }
    float r[ORD + 1];
#pragma unroll
    for (int j = 0; j <= ORD; ++j) {
        float p = 0.0f;
#pragma unroll
        for (int m = 0; m < CHUNK; ++m) p = fmaf(w[m], w[m + j], p);
        r[j] = p;
    }
    // reduce across the 8 lanes of the group (xor 1,2,4), broadcast to all
#pragma unroll
    for (int off = 4; off >= 1; off >>= 1) {
#pragma unroll
        for (int j = 0; j <= ORD; ++j) r[j] += __shfl_xor(r[j], off, 64);
    }

    // ---- Levinson-Durbin (redundant across the 8 lanes of the group) ----
    float a[ORD + 1], tmp[ORD + 1];
    a[0] = 1.0f;
#pragma unroll
    for (int j = 1; j <= ORD; ++j) a[j] = 0.0f;
    float e = r[0];
#pragma unroll
    for (int i = 1; i <= ORD; ++i) {
        float acc = r[i];
#pragma unroll
        for (int m = 1; m < i; ++m) acc -= a[m] * r[i - m];
        float k = acc * __builtin_amdgcn_rcpf(e);
#pragma unroll
        for (int m = 1; m < i; ++m) tmp[m] = a[m] - k * a[i - m];
#pragma unroll
        for (int m = 1; m < i; ++m) a[m] = tmp[m];
        a[i] = k;
        e *= (1.0f - k * k);
    }

    // ---- FIR from register window [c-16, c+20) ----
    float v[36];
    {
        const float* wf = fb + CHUNK * li;  // data-16 -> includes front pad, 16B-aligned
#pragma unroll
        for (int m = 0; m < 36; m += 4)
            *(float4*)(v + m) = *(const float4*)(wf + m);
    }
    float4* ob = (float4*)(out + (size_t)(wframe0 + g) * FS + CHUNK * li);
#pragma unroll
    for (int q = 0; q < 5; ++q) {
        float4 o;
#pragma unroll
        for (int u = 0; u < 4; ++u) {
            int m = 4 * q + u;           // t offset within chunk
            float acc2 = 0.0f;
#pragma unroll
            for (int j = 0; j <= ORD; ++j) acc2 = fmaf(a[j], v[16 + m - j], acc2);
            ((float*)&o)[u] = acc2;
        }
        ob[q] = o;
    }
}

extern "C" void kernel_launch(void* const* d_in, const int* in_sizes, int n_in,
                              void* d_out, int out_size, void* d_ws, size_t ws_size,
                              hipStream_t stream) {
    const float* x = (const float*)d_in[0];
    float* out = (float*)d_out;
    const int total = in_sizes[0];              // 5,120,000
    const int nframes = total / FS;             // 32,000
    const int blocks = (nframes + FPB - 1) / FPB;  // 1,000
    lpc_kernel<<<blocks, 256, 0, stream>>>(x, out, nframes);
}